// Round 6
// baseline (438.034 us; speedup 1.0000x reference)
//
#include <hip/hip_runtime.h>
#include <stdint.h>

namespace {
constexpr int Wd = 960, Hd = 544, Cd = 16, Id = 5, Bd = 2;
constexpr int HW = Hd * Wd;                       // 522240
constexpr long CHW = (long)Cd * HW;               // 8,355,840
constexpr long FRAME_BSTRIDE = (long)Id * CHW;
constexpr long FLOW_BSTRIDE  = (long)Id * 2 * HW;
constexpr long WS_BSTRIDE    = 3 * CHW;           // compact ws layout: 3 slots/batch

constexpr int TSX = 64, TSY = 32;   // output tile, 512 thr x 4 px
constexpr int HALO = 12;            // 3 sigma of 4px flow; tails -> global fallback
constexpr int TWX = TSX + 2 * HALO; // 88
constexpr int TWY = TSY + 2 * HALO; // 56
constexpr int NCHUNK = 20;                    // 20 x 256 floats = 5120 >= 88*56
constexpr int TILE_PAD = NCHUNK * 256 + 264;  // pad: bottom-row pair reads in-bounds
constexpr int GX = Wd / TSX;        // 15
constexpr int GY = Hd / TSY;        // 17
constexpr int NWG = GX * GY * Bd;   // 510
}

struct F2 { float x, y; };
struct FP { const float* s; long ss; float* d; long ds; };  // src/dst + batch strides

// Fused backward bilinear warp: NF frames share one flow field (mv[:, j]).
// Per block: decode tile, compute weights/addresses ONCE, then per frame x
// channel stage src tile into double-buffered LDS via global_load_lds and
// gather from LDS (global fallback for out-of-tile samples, weights carry
// zeros-padding validity).
template <int NF>
__global__ __launch_bounds__(512) void warp_tile_fused(
    FP p0, FP p1, FP p2, FP p3, const float* __restrict__ flow)
{
  __shared__ float tile[2][TILE_PAD];   // ~43 KB

  // XCD-aware bijective swizzle (m204).
  const int orig = blockIdx.x;
  const int xcd  = orig & 7;
  constexpr int q = NWG / 8, r = NWG % 8;  // 63, 6
  const int wgid = (xcd < r ? xcd * (q + 1) : r * (q + 1) + (xcd - r) * q)
                 + (orig >> 3);

  const int b   = wgid / (GX * GY);
  const int rem = wgid - b * (GX * GY);
  const int tyb = rem / GX;
  const int txb = rem - tyb * GX;
  const int X0 = txb * TSX;
  const int Y0 = tyb * TSY;

  const float* sF[4];
  float*       dF[4];
  sF[0] = p0.s + (long)b * p0.ss;  dF[0] = p0.d + (long)b * p0.ds;
  sF[1] = p1.s + (long)b * p1.ss;  dF[1] = p1.d + (long)b * p1.ds;
  sF[2] = p2.s + (long)b * p2.ss;  dF[2] = p2.d + (long)b * p2.ds;
  sF[3] = p3.s + (long)b * p3.ss;  dF[3] = p3.d + (long)b * p3.ds;
  const float* fl = flow + (long)b * FLOW_BSTRIDE;

  // Thread -> 4 consecutive x px, one row. 512 thr = 64x32 tile.
  const int t   = threadIdx.x;
  const int x   = X0 + ((t & 15) << 2);
  const int y   = Y0 + (t >> 4);
  const int pix = y * Wd + x;

  float4 fxv = *reinterpret_cast<const float4*>(fl + pix);
  float4 fyv = *reinterpret_cast<const float4*>(fl + HW + pix);

  float w00[4], w10[4], w01[4], w11[4];
  int   lA[4];                       // LDS byte addr of corner00, or -1
  int   g00[4], g10[4], g01[4], g11[4];

#pragma unroll
  for (int j = 0; j < 4; ++j) {
    float fx = (j == 0) ? fxv.x : (j == 1) ? fxv.y : (j == 2) ? fxv.z : fxv.w;
    float fy = (j == 0) ? fyv.x : (j == 1) ? fyv.y : (j == 2) ? fyv.z : fyv.w;
    float gx = (float)(x + j) + fx;
    float gy = (float)y + fy;
    float x0f = floorf(gx), y0f = floorf(gy);
    float wx = gx - x0f, wy = gy - y0f;
    bool vx0 = (x0f >= 0.f) && (x0f <= (float)(Wd - 1));
    bool vx1 = (x0f + 1.f >= 0.f) && (x0f + 1.f <= (float)(Wd - 1));
    bool vy0 = (y0f >= 0.f) && (y0f <= (float)(Hd - 1));
    bool vy1 = (y0f + 1.f >= 0.f) && (y0f + 1.f <= (float)(Hd - 1));
    w00[j] = (1.f - wx) * (1.f - wy) * ((vx0 && vy0) ? 1.f : 0.f);
    w10[j] = wx * (1.f - wy)         * ((vx1 && vy0) ? 1.f : 0.f);
    w01[j] = (1.f - wx) * wy         * ((vx0 && vy1) ? 1.f : 0.f);
    w11[j] = wx * wy                 * ((vx1 && vy1) ? 1.f : 0.f);
    int ix0 = (int)x0f;
    int iy0 = (int)y0f;
    int lx = ix0 - (X0 - HALO);
    int ly = iy0 - (Y0 - HALO);
    bool ft = (lx >= 0) & (lx <= TWX - 2) & (ly >= 0) & (ly <= TWY - 2);
    lA[j] = ft ? (ly * TWX + lx) * 4 : -1;
    int xc0 = min(max(ix0, 0), Wd - 1), xc1 = min(max(ix0 + 1, 0), Wd - 1);
    int yc0 = min(max(iy0, 0), Hd - 1), yc1 = min(max(iy0 + 1, 0), Hd - 1);
    g00[j] = yc0 * Wd + xc0;
    g10[j] = yc0 * Wd + xc1;
    g01[j] = yc1 * Wd + xc0;
    g11[j] = yc1 * Wd + xc1;
  }

  // Fill plumbing: 20 chunks of 256 floats (1 KB). Wave wv owns chunks
  // {wv, wv+8, wv+16<20}. Global offsets fixed across frames/channels.
  const int lane = t & 63;
  const int wv   = t >> 6;
  const int nck  = (wv < 4) ? 3 : 2;
  int goff[3];
#pragma unroll
  for (int k = 0; k < 3; ++k) {
    int ck = wv + 8 * k;
    if (ck < NCHUNK) {
      int foff = ck * 256 + lane * 4;
      int ly = foff / TWX;
      int lx = foff - ly * TWX;
      int gxc = min(max(X0 - HALO + lx, 0), Wd - 4);  // clamped cells feed w=0 only
      int gyc = min(max(Y0 - HALO + ly, 0), Hd - 1);
      goff[k] = gyc * Wd + gxc;
    }
  }

  auto fill = [&](int nb, const float* sC) {
#pragma unroll
    for (int k = 0; k < 3; ++k) {
      if (k < nck) {
        __builtin_amdgcn_global_load_lds(
            (__attribute__((address_space(1))) void*)(void*)(sC + goff[k]),
            (__attribute__((address_space(3))) void*)&tile[nb][(wv + 8 * k) * 256],
            16, 0, 0);
      }
    }
  };

  fill(0, sF[0]);

#pragma unroll
  for (int f = 0; f < NF; ++f) {
#pragma unroll
    for (int c = 0; c < Cd; ++c) {
      const int it = f * Cd + c;          // global iteration (compile-time)
      const int cur = it & 1;
      __syncthreads();                    // buf[cur] ready; prior reads done
      if (it + 1 < NF * Cd) {
        const int nf = (c == Cd - 1) ? f + 1 : f;
        const int nc = (c == Cd - 1) ? 0 : c + 1;
        fill(cur ^ 1, sF[nf] + (long)nc * HW);
      }
      const float* sC = sF[f] + (long)c * HW;
      const float* tb = tile[cur];
      float ov[4];
#pragma unroll
      for (int j = 0; j < 4; ++j) {
        float v;
        if (lA[j] >= 0) {
          F2 r0 = *(const F2*)((const char*)tb + lA[j]);
          F2 r1 = *(const F2*)((const char*)tb + lA[j] + TWX * 4);
          v = (w00[j] * r0.x + w10[j] * r0.y) + (w01[j] * r1.x + w11[j] * r1.y);
        } else {
          v = w00[j] * sC[g00[j]] + w10[j] * sC[g10[j]]
            + w01[j] * sC[g01[j]] + w11[j] * sC[g11[j]];
        }
        ov[j] = v;
      }
      *reinterpret_cast<float4*>(dF[f] + (long)c * HW + pix)
          = make_float4(ov[0], ov[1], ov[2], ov[3]);
    }
  }
}

extern "C" void kernel_launch(void* const* d_in, const int* in_sizes, int n_in,
                              void* d_out, int out_size, void* d_ws, size_t ws_size,
                              hipStream_t stream) {
  const float* feat = (const float*)d_in[0];
  const float* mv   = (const float*)d_in[1];
  float*       out  = (float*)d_out;
  float*       ws   = (float*)d_ws;

  dim3 block(512, 1, 1);
  dim3 grid(NWG, 1, 1);

  const long FB = FRAME_BSTRIDE, WB = WS_BSTRIDE;
  auto fp = [](const float* s, long ss, float* d, long ds) {
    FP p; p.s = s; p.ss = ss; p.d = d; p.ds = ds; return p;
  };
  FP Z = fp(nullptr, 0, nullptr, 0);

  const float* flj[4] = { mv + 0L * 2 * HW, mv + 1L * 2 * HW,
                          mv + 2L * 2 * HW, mv + 3L * 2 * HW };

  if (ws_size >= (size_t)(WS_BSTRIDE * Bd * sizeof(float))) {
    // Fused path: 4 dispatches, one per mv level j = 3..0.
    // ws slot A(f) = ws + (f-2)*CHW, batch stride WB (f in {2,3,4}).
    float* A2 = ws + 0 * CHW;
    float* A3 = ws + 1 * CHW;
    float* A4 = ws + 2 * CHW;
    // j=3: frame 4: feat -> A4
    warp_tile_fused<1><<<grid, block, 0, stream>>>(
        fp(feat + 4 * CHW, FB, A4, WB), Z, Z, Z, flj[3]);
    // j=2: frame 3: feat -> out3 ; frame 4: A4 -> out4
    warp_tile_fused<2><<<grid, block, 0, stream>>>(
        fp(feat + 3 * CHW, FB, out + 3 * CHW, FB),
        fp(A4, WB, out + 4 * CHW, FB), Z, Z, flj[2]);
    // j=1: frame 2: feat -> A2 ; frame 3: out3 -> A3 ; frame 4: out4 -> A4
    warp_tile_fused<3><<<grid, block, 0, stream>>>(
        fp(feat + 2 * CHW, FB, A2, WB),
        fp(out + 3 * CHW, FB, A3, WB),
        fp(out + 4 * CHW, FB, A4, WB), Z, flj[1]);
    // j=0: frame 1: feat -> out1 ; frames 2..4: A -> out
    warp_tile_fused<4><<<grid, block, 0, stream>>>(
        fp(feat + 1 * CHW, FB, out + 1 * CHW, FB),
        fp(A2, WB, out + 2 * CHW, FB),
        fp(A3, WB, out + 3 * CHW, FB),
        fp(A4, WB, out + 4 * CHW, FB), flj[0]);
  } else {
    // Fallback (round-5 proven): 10 NF=1 dispatches, frame-0 slot as scratch.
    float* S = out;  // per batch: out + b*FB + 0*CHW
    auto warp1 = [&](const float* s, float* d, int j) {
      warp_tile_fused<1><<<grid, block, 0, stream>>>(
          fp(s, FB, d, FB), Z, Z, Z, flj[j]);
    };
    warp1(feat + 1 * CHW, out + 1 * CHW, 0);
    warp1(feat + 2 * CHW, S, 1);
    warp1(S, out + 2 * CHW, 0);
    warp1(feat + 3 * CHW, out + 3 * CHW, 2);
    warp1(out + 3 * CHW, S, 1);
    warp1(S, out + 3 * CHW, 0);
    warp1(feat + 4 * CHW, S, 3);
    warp1(S, out + 4 * CHW, 2);
    warp1(out + 4 * CHW, S, 1);
    warp1(S, out + 4 * CHW, 0);
  }

  // frame 0: plain copy (after any scratch use of the frame-0 slot).
  for (int b = 0; b < Bd; ++b) {
    hipMemcpyAsync(out + (long)b * FRAME_BSTRIDE,
                   feat + (long)b * FRAME_BSTRIDE,
                   CHW * sizeof(float), hipMemcpyDeviceToDevice, stream);
  }
}

// Round 7
// 375.050 us; speedup vs baseline: 1.1679x; 1.1679x over previous
//
#include <hip/hip_runtime.h>
#include <stdint.h>

namespace {
constexpr int Wd = 960, Hd = 544, Cd = 16, Id = 5, Bd = 2;
constexpr int HW = Hd * Wd;                       // 522240
constexpr long CHW = (long)Cd * HW;               // 8,355,840
constexpr long FRAME_BSTRIDE = (long)Id * CHW;
constexpr long FLOW_BSTRIDE  = (long)Id * 2 * HW;

constexpr int TSX = 64, TSY = 32;   // output tile, 512 thr x 4 px
constexpr int HALO = 12;            // 3 sigma of 4px flow; tails -> global fallback
constexpr int TWX = TSX + 2 * HALO; // 88
constexpr int TWY = TSY + 2 * HALO; // 56
constexpr int NCHUNK = 20;          // 20 x 256 floats = 5120 >= 88*56 = 4928
constexpr int TILE_F = NCHUNK * 256;  // 5120; max gather read idx 4927 (verified)
constexpr int GX = Wd / TSX;        // 15
constexpr int GY = Hd / TSY;        // 17
constexpr int NWG = GX * GY * Bd;   // 510
}

struct F2 { float x, y; };
// One frame-warp job: dst <- warp(src, flow). fl == nullptr -> plain copy.
struct Job { const float* s; long ss; float* d; long ds; const float* fl; };

// blockIdx.y selects the job (uniform branch; body identical to round-5
// proven kernel). blockIdx.x = tile, XCD-bijective swizzled.
__global__ __launch_bounds__(512) void warp_jobs(
    Job j0, Job j1, Job j2, Job j3, Job j4)
{
  __shared__ float tile[2][TILE_F];   // 40 KB exactly

  const int jb = blockIdx.y;
  Job J = j0;
  if      (jb == 1) J = j1;
  else if (jb == 2) J = j2;
  else if (jb == 3) J = j3;
  else if (jb == 4) J = j4;

  // XCD-aware bijective swizzle (m204).
  const int orig = blockIdx.x;
  const int xcd  = orig & 7;
  constexpr int q = NWG / 8, r = NWG % 8;  // 63, 6
  const int wgid = (xcd < r ? xcd * (q + 1) : r * (q + 1) + (xcd - r) * q)
                 + (orig >> 3);

  const int b   = wgid / (GX * GY);
  const int rem = wgid - b * (GX * GY);
  const int tyb = rem / GX;
  const int txb = rem - tyb * GX;
  const int X0 = txb * TSX;
  const int Y0 = tyb * TSY;

  const float* sF = J.s + (long)b * J.ss;
  float*       dF = J.d + (long)b * J.ds;

  const int t   = threadIdx.x;
  const int x   = X0 + ((t & 15) << 2);
  const int y   = Y0 + (t >> 4);
  const int pix = y * Wd + x;

  if (J.fl == nullptr) {   // plain copy job (frame 0)
#pragma unroll
    for (int c = 0; c < Cd; ++c)
      *reinterpret_cast<float4*>(dF + (long)c * HW + pix)
          = *reinterpret_cast<const float4*>(sF + (long)c * HW + pix);
    return;
  }

  const float* fl = J.fl + (long)b * FLOW_BSTRIDE;
  float4 fxv = *reinterpret_cast<const float4*>(fl + pix);
  float4 fyv = *reinterpret_cast<const float4*>(fl + HW + pix);

  float w00[4], w10[4], w01[4], w11[4];
  int   lA[4];                       // LDS byte addr of corner00, or -1
  int   g00[4], g10[4], g01[4], g11[4];

#pragma unroll
  for (int j = 0; j < 4; ++j) {
    float fx = (j == 0) ? fxv.x : (j == 1) ? fxv.y : (j == 2) ? fxv.z : fxv.w;
    float fy = (j == 0) ? fyv.x : (j == 1) ? fyv.y : (j == 2) ? fyv.z : fyv.w;
    float gx = (float)(x + j) + fx;
    float gy = (float)y + fy;
    float x0f = floorf(gx), y0f = floorf(gy);
    float wx = gx - x0f, wy = gy - y0f;
    bool vx0 = (x0f >= 0.f) && (x0f <= (float)(Wd - 1));
    bool vx1 = (x0f + 1.f >= 0.f) && (x0f + 1.f <= (float)(Wd - 1));
    bool vy0 = (y0f >= 0.f) && (y0f <= (float)(Hd - 1));
    bool vy1 = (y0f + 1.f >= 0.f) && (y0f + 1.f <= (float)(Hd - 1));
    w00[j] = (1.f - wx) * (1.f - wy) * ((vx0 && vy0) ? 1.f : 0.f);
    w10[j] = wx * (1.f - wy)         * ((vx1 && vy0) ? 1.f : 0.f);
    w01[j] = (1.f - wx) * wy         * ((vx0 && vy1) ? 1.f : 0.f);
    w11[j] = wx * wy                 * ((vx1 && vy1) ? 1.f : 0.f);
    int ix0 = (int)x0f;
    int iy0 = (int)y0f;
    int lx = ix0 - (X0 - HALO);
    int ly = iy0 - (Y0 - HALO);
    bool ft = (lx >= 0) & (lx <= TWX - 2) & (ly >= 0) & (ly <= TWY - 2);
    lA[j] = ft ? (ly * TWX + lx) * 4 : -1;
    int xc0 = min(max(ix0, 0), Wd - 1), xc1 = min(max(ix0 + 1, 0), Wd - 1);
    int yc0 = min(max(iy0, 0), Hd - 1), yc1 = min(max(iy0 + 1, 0), Hd - 1);
    g00[j] = yc0 * Wd + xc0;
    g10[j] = yc0 * Wd + xc1;
    g01[j] = yc1 * Wd + xc0;
    g11[j] = yc1 * Wd + xc1;
  }

  // Fill plumbing: 20 chunks of 256 floats. Wave wv owns {wv, wv+8, wv+16<20}.
  const int lane = t & 63;
  const int wv   = t >> 6;
  const int nck  = (wv < 4) ? 3 : 2;
  int goff[3];
#pragma unroll
  for (int k = 0; k < 3; ++k) {
    int ck = wv + 8 * k;
    if (ck < NCHUNK) {
      int foff = ck * 256 + lane * 4;
      int ly = foff / TWX;
      int lx = foff - ly * TWX;
      int gxc = min(max(X0 - HALO + lx, 0), Wd - 4);  // clamped cells feed w=0 only
      int gyc = min(max(Y0 - HALO + ly, 0), Hd - 1);
      goff[k] = gyc * Wd + gxc;
    }
  }

  auto fill = [&](int nb, const float* sC) {
#pragma unroll
    for (int k = 0; k < 3; ++k) {
      if (k < nck) {
        __builtin_amdgcn_global_load_lds(
            (__attribute__((address_space(1))) void*)(void*)(sC + goff[k]),
            (__attribute__((address_space(3))) void*)&tile[nb][(wv + 8 * k) * 256],
            16, 0, 0);
      }
    }
  };

  fill(0, sF);

#pragma unroll
  for (int c = 0; c < Cd; ++c) {
    __syncthreads();                        // buf[c&1] ready; prior reads done
    if (c + 1 < Cd) fill((c + 1) & 1, sF + (long)(c + 1) * HW);
    const float* sC = sF + (long)c * HW;
    const float* tb = tile[c & 1];
    float ov[4];
#pragma unroll
    for (int j = 0; j < 4; ++j) {
      float v;
      if (lA[j] >= 0) {
        F2 r0 = *(const F2*)((const char*)tb + lA[j]);
        F2 r1 = *(const F2*)((const char*)tb + lA[j] + TWX * 4);
        v = (w00[j] * r0.x + w10[j] * r0.y) + (w01[j] * r1.x + w11[j] * r1.y);
      } else {
        v = w00[j] * sC[g00[j]] + w10[j] * sC[g10[j]]
          + w01[j] * sC[g01[j]] + w11[j] * sC[g11[j]];
      }
      ov[j] = v;
    }
    *reinterpret_cast<float4*>(dF + (long)c * HW + pix)
        = make_float4(ov[0], ov[1], ov[2], ov[3]);
  }
}

extern "C" void kernel_launch(void* const* d_in, const int* in_sizes, int n_in,
                              void* d_out, int out_size, void* d_ws, size_t ws_size,
                              hipStream_t stream) {
  const float* feat = (const float*)d_in[0];
  const float* mv   = (const float*)d_in[1];
  float*       out  = (float*)d_out;
  float*       ws   = (float*)d_ws;

  dim3 block(512, 1, 1);
  const long FB = FRAME_BSTRIDE;
  auto mkjob = [](const float* s, long ss, float* d, long ds, const float* fl) {
    Job j; j.s = s; j.ss = ss; j.d = d; j.ds = ds; j.fl = fl; return j;
  };
  Job Z = mkjob(nullptr, 0, nullptr, 0, nullptr);
  const float* flj[4] = { mv + 0L * 2 * HW, mv + 1L * 2 * HW,
                          mv + 2L * 2 * HW, mv + 3L * 2 * HW };

  auto launch = [&](int nj, Job a, Job b, Job c, Job d, Job e) {
    warp_jobs<<<dim3(NWG, nj, 1), block, 0, stream>>>(a, b, c, d, e);
  };

  const size_t need4 = (size_t)(4 * CHW) * Bd * sizeof(float);
  const size_t need3 = (size_t)(3 * CHW) * Bd * sizeof(float);

  if (ws_size >= need4) {
    // 4 ws slots per batch, stride 4*CHW. out4 doubles as a stage-B/C temp.
    const long WB = 4 * CHW;
    float* W0 = ws + 0 * CHW;
    float* W1 = ws + 1 * CHW;
    float* W2 = ws + 2 * CHW;
    float* W3 = ws + 3 * CHW;
    // A: f1 final; f2,f3,f4 first warps; frame-0 copy.
    launch(5,
      mkjob(feat + 1 * CHW, FB, out + 1 * CHW, FB, flj[0]),
      mkjob(feat + 2 * CHW, FB, W0, WB, flj[1]),
      mkjob(feat + 3 * CHW, FB, W1, WB, flj[2]),
      mkjob(feat + 4 * CHW, FB, W2, WB, flj[3]),
      mkjob(feat + 0 * CHW, FB, out + 0 * CHW, FB, nullptr));
    // B: reads W0,W1,W2; writes out2(final), W3, out4(temp).
    launch(3,
      mkjob(W0, WB, out + 2 * CHW, FB, flj[0]),
      mkjob(W1, WB, W3, WB, flj[1]),
      mkjob(W2, WB, out + 4 * CHW, FB, flj[2]), Z, Z);
    // C: reads W3, out4; writes out3(final), W0.
    launch(2,
      mkjob(W3, WB, out + 3 * CHW, FB, flj[0]),
      mkjob(out + 4 * CHW, FB, W0, WB, flj[1]), Z, Z, Z);
    // D: W0 -> out4 final.
    launch(1, mkjob(W0, WB, out + 4 * CHW, FB, flj[0]), Z, Z, Z, Z);
  } else if (ws_size >= need3) {
    // 3 ws slots; frame-0 slot of out is the 4th scratch; trailing copy.
    const long WB = 3 * CHW;
    float* W0 = ws + 0 * CHW;
    float* W1 = ws + 1 * CHW;
    float* W2 = ws + 2 * CHW;
    float* S  = out;  // out0 slot, batch stride FB
    launch(4,
      mkjob(feat + 1 * CHW, FB, out + 1 * CHW, FB, flj[0]),
      mkjob(feat + 2 * CHW, FB, W0, WB, flj[1]),
      mkjob(feat + 3 * CHW, FB, W1, WB, flj[2]),
      mkjob(feat + 4 * CHW, FB, W2, WB, flj[3]), Z);
    launch(3,
      mkjob(W0, WB, out + 2 * CHW, FB, flj[0]),
      mkjob(W1, WB, S, FB, flj[1]),
      mkjob(W2, WB, out + 4 * CHW, FB, flj[2]), Z, Z);
    launch(2,
      mkjob(S, FB, out + 3 * CHW, FB, flj[0]),
      mkjob(out + 4 * CHW, FB, W0, WB, flj[1]), Z, Z, Z);
    launch(1, mkjob(W0, WB, out + 4 * CHW, FB, flj[0]), Z, Z, Z, Z);
    launch(1, mkjob(feat, FB, out, FB, nullptr), Z, Z, Z, Z);  // frame-0 copy
  } else {
    // Proven round-5 fallback: 10 single-job dispatches, out0 as scratch.
    float* S = out;
    auto w1 = [&](const float* s, float* d, int j) {
      launch(1, mkjob(s, FB, d, FB, flj[j]), Z, Z, Z, Z);
    };
    w1(feat + 1 * CHW, out + 1 * CHW, 0);
    w1(feat + 2 * CHW, S, 1);
    w1(S, out + 2 * CHW, 0);
    w1(feat + 3 * CHW, out + 3 * CHW, 2);
    w1(out + 3 * CHW, S, 1);
    w1(S, out + 3 * CHW, 0);
    w1(feat + 4 * CHW, S, 3);
    w1(S, out + 4 * CHW, 2);
    w1(out + 4 * CHW, S, 1);
    w1(S, out + 4 * CHW, 0);
    launch(1, mkjob(feat, FB, out, FB, nullptr), Z, Z, Z, Z);  // frame-0 copy
  }
}

// Round 8
// 339.239 us; speedup vs baseline: 1.2912x; 1.1056x over previous
//
#include <hip/hip_runtime.h>
#include <stdint.h>

namespace {
constexpr int Wd = 960, Hd = 544, Cd = 16, Id = 5, Bd = 2;
constexpr int HW = Hd * Wd;                       // 522240
constexpr long CHW = (long)Cd * HW;               // 8,355,840
constexpr long FRAME_BSTRIDE = (long)Id * CHW;
constexpr long FLOW_BSTRIDE  = (long)Id * 2 * HW;

constexpr int TSX = 64, TSY = 32;   // output tile, 512 thr x 4 px
constexpr int HALO = 12;            // 3 sigma of 4px flow; tails -> global fallback
constexpr int TWX = TSX + 2 * HALO; // 88
constexpr int TWY = TSY + 2 * HALO; // 56
constexpr int NCHUNK = 20;          // 20 x 256 floats = 5120 >= 88*56 = 4928
constexpr int TILE_F = NCHUNK * 256;
constexpr int GX = Wd / TSX;        // 15
constexpr int GY = Hd / TSY;        // 17
constexpr int NWG = GX * GY * Bd;   // 510
}

struct F2 { float x, y; };
// One frame-warp job. s/d base pointers with batch strides in ELEMENTS of
// their own dtype (fp32 or bf16 per sBF/dBF). fl==nullptr -> fp32 copy.
struct Job {
  const void* s; long ss;
  void*       d; long ds;
  const float* fl;
  int sBF, dBF;
};

__device__ __forceinline__ uint f2bf_bits(float v) {   // RNE float->bf16
  uint x = __float_as_uint(v);
  return (x + 0x7FFFu + ((x >> 16) & 1u)) >> 16;
}

__global__ __launch_bounds__(512) void warp_jobs(
    Job j0, Job j1, Job j2, Job j3, Job j4)
{
  __shared__ float tile[2][TILE_F];   // 40 KB (fp32 regardless of src dtype)

  const int jb = blockIdx.y;
  Job J = j0;
  if      (jb == 1) J = j1;
  else if (jb == 2) J = j2;
  else if (jb == 3) J = j3;
  else if (jb == 4) J = j4;

  // XCD-aware bijective swizzle (m204).
  const int orig = blockIdx.x;
  const int xcd  = orig & 7;
  constexpr int q = NWG / 8, r = NWG % 8;  // 63, 6
  const int wgid = (xcd < r ? xcd * (q + 1) : r * (q + 1) + (xcd - r) * q)
                 + (orig >> 3);

  const int b   = wgid / (GX * GY);
  const int rem = wgid - b * (GX * GY);
  const int tyb = rem / GX;
  const int txb = rem - tyb * GX;
  const int X0 = txb * TSX;
  const int Y0 = tyb * TSY;

  const int t   = threadIdx.x;
  const int x   = X0 + ((t & 15) << 2);
  const int y   = Y0 + (t >> 4);
  const int pix = y * Wd + x;

  const float*    sF32 = (const float*)J.s + (long)b * J.ss;
  float*          dF32 = (float*)J.d + (long)b * J.ds;
  const uint16_t* sB16 = (const uint16_t*)J.s + (long)b * J.ss;
  uint16_t*       dB16 = (uint16_t*)J.d + (long)b * J.ds;
  const bool sBF = J.sBF != 0;
  const bool dBF = J.dBF != 0;

  if (J.fl == nullptr) {   // plain fp32 copy job (frame 0)
#pragma unroll
    for (int c = 0; c < Cd; ++c)
      *reinterpret_cast<float4*>(dF32 + (long)c * HW + pix)
          = *reinterpret_cast<const float4*>(sF32 + (long)c * HW + pix);
    return;
  }

  const float* fl = J.fl + (long)b * FLOW_BSTRIDE;
  float4 fxv = *reinterpret_cast<const float4*>(fl + pix);
  float4 fyv = *reinterpret_cast<const float4*>(fl + HW + pix);

  float w00[4], w10[4], w01[4], w11[4];
  int   lA[4];                       // LDS byte addr of corner00, or -1
  int   g00[4], g10[4], g01[4], g11[4];

#pragma unroll
  for (int j = 0; j < 4; ++j) {
    float fx = (j == 0) ? fxv.x : (j == 1) ? fxv.y : (j == 2) ? fxv.z : fxv.w;
    float fy = (j == 0) ? fyv.x : (j == 1) ? fyv.y : (j == 2) ? fyv.z : fyv.w;
    float gx = (float)(x + j) + fx;
    float gy = (float)y + fy;
    float x0f = floorf(gx), y0f = floorf(gy);
    float wx = gx - x0f, wy = gy - y0f;
    bool vx0 = (x0f >= 0.f) && (x0f <= (float)(Wd - 1));
    bool vx1 = (x0f + 1.f >= 0.f) && (x0f + 1.f <= (float)(Wd - 1));
    bool vy0 = (y0f >= 0.f) && (y0f <= (float)(Hd - 1));
    bool vy1 = (y0f + 1.f >= 0.f) && (y0f + 1.f <= (float)(Hd - 1));
    w00[j] = (1.f - wx) * (1.f - wy) * ((vx0 && vy0) ? 1.f : 0.f);
    w10[j] = wx * (1.f - wy)         * ((vx1 && vy0) ? 1.f : 0.f);
    w01[j] = (1.f - wx) * wy         * ((vx0 && vy1) ? 1.f : 0.f);
    w11[j] = wx * wy                 * ((vx1 && vy1) ? 1.f : 0.f);
    int ix0 = (int)x0f;
    int iy0 = (int)y0f;
    int lx = ix0 - (X0 - HALO);
    int ly = iy0 - (Y0 - HALO);
    bool ft = (lx >= 0) & (lx <= TWX - 2) & (ly >= 0) & (ly <= TWY - 2);
    lA[j] = ft ? (ly * TWX + lx) * 4 : -1;
    int xc0 = min(max(ix0, 0), Wd - 1), xc1 = min(max(ix0 + 1, 0), Wd - 1);
    int yc0 = min(max(iy0, 0), Hd - 1), yc1 = min(max(iy0 + 1, 0), Hd - 1);
    g00[j] = yc0 * Wd + xc0;
    g10[j] = yc0 * Wd + xc1;
    g01[j] = yc1 * Wd + xc0;
    g11[j] = yc1 * Wd + xc1;
  }

  // Fill plumbing: 20 chunks of 256 floats. Wave wv owns {wv, wv+8, wv+16<20}.
  // goff[k] = per-lane global ELEMENT index (mult of 4), same for fp32/bf16.
  const int lane = t & 63;
  const int wv   = t >> 6;
  const int nck  = (wv < 4) ? 3 : 2;
  int goff[3];
#pragma unroll
  for (int k = 0; k < 3; ++k) {
    int ck = wv + 8 * k;
    if (ck < NCHUNK) {
      int foff = ck * 256 + lane * 4;
      int ly = foff / TWX;
      int lx = foff - ly * TWX;
      int gxc = min(max(X0 - HALO + lx, 0), Wd - 4);  // clamped cells feed w=0 only
      int gyc = min(max(Y0 - HALO + ly, 0), Hd - 1);
      goff[k] = gyc * Wd + gxc;
    }
  }

  // fp32 fill: async global->LDS.
  auto fill32 = [&](int nb, int c) {
    const float* sC = sF32 + (long)c * HW;
#pragma unroll
    for (int k = 0; k < 3; ++k) {
      if (k < nck) {
        __builtin_amdgcn_global_load_lds(
            (__attribute__((address_space(1))) void*)(void*)(sC + goff[k]),
            (__attribute__((address_space(3))) void*)&tile[nb][(wv + 8 * k) * 256],
            16, 0, 0);
      }
    }
  };

  // bf16 fill: reg-staged (load early / cvt+ds_write late, T14 split).
  uint2 ld[3];
  auto loadB = [&](int c) {
    const uint* gp = (const uint*)(sB16 + (long)c * HW);
#pragma unroll
    for (int k = 0; k < 3; ++k)
      if (k < nck) ld[k] = *(const uint2*)(gp + (goff[k] >> 1));  // 8B aligned
  };
  auto writeB = [&](int nb) {
#pragma unroll
    for (int k = 0; k < 3; ++k) {
      if (k < nck) {
        float4 f;
        f.x = __uint_as_float(ld[k].x << 16);
        f.y = __uint_as_float(ld[k].x & 0xFFFF0000u);
        f.z = __uint_as_float(ld[k].y << 16);
        f.w = __uint_as_float(ld[k].y & 0xFFFF0000u);
        *reinterpret_cast<float4*>(&tile[nb][(wv + 8 * k) * 256 + lane * 4]) = f;
      }
    }
  };

  if (sBF) { loadB(0); writeB(0); } else fill32(0, 0);

#pragma unroll
  for (int c = 0; c < Cd; ++c) {
    __syncthreads();                        // buf[c&1] ready; prior reads done
    const bool pre = (c + 1 < Cd);
    if (pre) { if (sBF) loadB(c + 1); else fill32((c + 1) & 1, c + 1); }

    const float* tb = tile[c & 1];
    float ov[4];
#pragma unroll
    for (int j = 0; j < 4; ++j) {
      float v;
      if (lA[j] >= 0) {
        F2 r0 = *(const F2*)((const char*)tb + lA[j]);
        F2 r1 = *(const F2*)((const char*)tb + lA[j] + TWX * 4);
        v = (w00[j] * r0.x + w10[j] * r0.y) + (w01[j] * r1.x + w11[j] * r1.y);
      } else if (sBF) {
        const uint16_t* su = sB16 + (long)c * HW;
        float v00 = __uint_as_float((uint)su[g00[j]] << 16);
        float v10 = __uint_as_float((uint)su[g10[j]] << 16);
        float v01 = __uint_as_float((uint)su[g01[j]] << 16);
        float v11 = __uint_as_float((uint)su[g11[j]] << 16);
        v = w00[j] * v00 + w10[j] * v10 + w01[j] * v01 + w11[j] * v11;
      } else {
        const float* sC = sF32 + (long)c * HW;
        v = w00[j] * sC[g00[j]] + w10[j] * sC[g10[j]]
          + w01[j] * sC[g01[j]] + w11[j] * sC[g11[j]];
      }
      ov[j] = v;
    }
    if (dBF) {
      uint p0 = f2bf_bits(ov[0]) | (f2bf_bits(ov[1]) << 16);
      uint p1 = f2bf_bits(ov[2]) | (f2bf_bits(ov[3]) << 16);
      *reinterpret_cast<uint2*>(dB16 + (long)c * HW + pix) = make_uint2(p0, p1);
    } else {
      *reinterpret_cast<float4*>(dF32 + (long)c * HW + pix)
          = make_float4(ov[0], ov[1], ov[2], ov[3]);
    }
    if (pre && sBF) writeB((c + 1) & 1);    // after compute: hides HBM latency
  }
}

extern "C" void kernel_launch(void* const* d_in, const int* in_sizes, int n_in,
                              void* d_out, int out_size, void* d_ws, size_t ws_size,
                              hipStream_t stream) {
  const float* feat = (const float*)d_in[0];
  const float* mv   = (const float*)d_in[1];
  float*       out  = (float*)d_out;

  dim3 block(512, 1, 1);
  const long FB = FRAME_BSTRIDE;
  auto mkjob = [](const void* s, long ss, void* d, long ds, const float* fl,
                  int sBF, int dBF) {
    Job j; j.s = s; j.ss = ss; j.d = d; j.ds = ds; j.fl = fl;
    j.sBF = sBF; j.dBF = dBF; return j;
  };
  Job Z = mkjob(nullptr, 0, nullptr, 0, nullptr, 0, 0);
  const float* flj[4] = { mv + 0L * 2 * HW, mv + 1L * 2 * HW,
                          mv + 2L * 2 * HW, mv + 3L * 2 * HW };

  auto launch = [&](int nj, Job a, Job b, Job c, Job d, Job e) {
    warp_jobs<<<dim3(NWG, nj, 1), block, 0, stream>>>(a, b, c, d, e);
  };

  const size_t need = (size_t)(4 * CHW) * Bd * sizeof(uint16_t);  // 134 MB

  if (ws_size >= need) {
    // bf16 intermediates: 4 ws slots (a,b,d,c) + bf16 view of out4 slot (e);
    // f reuses slot a (dead after stage B).
    uint16_t* W  = (uint16_t*)d_ws;
    const long WB = 4 * CHW;               // ws batch stride (bf16 elems)
    uint16_t* wa = W + 0 * CHW;
    uint16_t* wb = W + 1 * CHW;
    uint16_t* wd = W + 2 * CHW;
    uint16_t* wc = W + 3 * CHW;
    uint16_t* we = (uint16_t*)(out + 4 * CHW);   // out4 slot as bf16 scratch
    const long EB = 2 * FB;                // out batch stride in bf16 elems

    // A: f1 final; f2->a, f3->b, f4->d (bf16); frame-0 copy.
    launch(5,
      mkjob(feat + 1 * CHW, FB, out + 1 * CHW, FB, flj[0], 0, 0),
      mkjob(feat + 2 * CHW, FB, wa, WB, flj[1], 0, 1),
      mkjob(feat + 3 * CHW, FB, wb, WB, flj[2], 0, 1),
      mkjob(feat + 4 * CHW, FB, wd, WB, flj[3], 0, 1),
      mkjob(feat, FB, out, FB, nullptr, 0, 0));
    // B: a->out2 final; b->c (bf16); d->e (bf16, in out4 slot).
    launch(3,
      mkjob(wa, WB, out + 2 * CHW, FB, flj[0], 1, 0),
      mkjob(wb, WB, wc, WB, flj[1], 1, 1),
      mkjob(wd, WB, we, EB, flj[2], 1, 1), Z, Z);
    // C: c->out3 final; e->f (bf16, reuse slot a).
    launch(2,
      mkjob(wc, WB, out + 3 * CHW, FB, flj[0], 1, 0),
      mkjob(we, EB, wa, WB, flj[1], 1, 1), Z, Z, Z);
    // D: f->out4 final (overwrites e, dead).
    launch(1, mkjob(wa, WB, out + 4 * CHW, FB, flj[0], 1, 0), Z, Z, Z, Z);
  } else {
    // Proven round-5 fallback: all-fp32, out0 slot as scratch, copy last.
    float* S = out;
    auto w1 = [&](const float* s, float* d, int j) {
      launch(1, mkjob(s, FB, d, FB, flj[j], 0, 0), Z, Z, Z, Z);
    };
    w1(feat + 1 * CHW, out + 1 * CHW, 0);
    w1(feat + 2 * CHW, S, 1);
    w1(S, out + 2 * CHW, 0);
    w1(feat + 3 * CHW, out + 3 * CHW, 2);
    w1(out + 3 * CHW, S, 1);
    w1(S, out + 3 * CHW, 0);
    w1(feat + 4 * CHW, S, 3);
    w1(S, out + 4 * CHW, 2);
    w1(out + 4 * CHW, S, 1);
    w1(S, out + 4 * CHW, 0);
    launch(1, mkjob(feat, FB, out, FB, nullptr, 0, 0), Z, Z, Z, Z);
  }
}

// Round 9
// 300.616 us; speedup vs baseline: 1.4571x; 1.1285x over previous
//
#include <hip/hip_runtime.h>
#include <stdint.h>

namespace {
constexpr int Wd = 960, Hd = 544, Cd = 16, Id = 5, Bd = 2;
constexpr int HW = Hd * Wd;                       // 522240
constexpr long CHW = (long)Cd * HW;               // 8,355,840
constexpr long FRAME_BSTRIDE = (long)Id * CHW;
constexpr long FLOW_BSTRIDE  = (long)Id * 2 * HW;

constexpr int TSX = 64, TSY = 32;   // output tile, 512 thr x 4 px
constexpr int HALO = 12;            // 3 sigma of 4px flow; tails -> epilogue fixup
constexpr int TWX = TSX + 2 * HALO; // 88
constexpr int TWY = TSY + 2 * HALO; // 56
constexpr int NCHUNK = 20;          // 20 x 256 floats = 5120 >= 88*56 = 4928
constexpr int TILE_F = NCHUNK * 256;  // max read idx 54*88+86+89 = 4927 < 5120
constexpr int GX = Wd / TSX;        // 15
constexpr int GY = Hd / TSY;        // 17
constexpr int NWG = GX * GY * Bd;   // 510
}

struct F2 { float x, y; };
struct Job { const void* s; long ss; void* d; long ds; const float* fl; int sBF, dBF; };

__device__ __forceinline__ uint f2bf_bits(float v) {   // RNE float->bf16
  uint x = __float_as_uint(v);
  return (x + 0x7FFFu + ((x >> 16) & 1u)) >> 16;
}

// ---------- decode helpers (shared source shape between the two kernels) ----
#define DECODE_TILE()                                                        \
  const int orig = blockIdx.x;                                               \
  const int xcd  = orig & 7;                                                 \
  constexpr int q = NWG / 8, r = NWG % 8;                                    \
  const int wgid = (xcd < r ? xcd * (q + 1) : r * (q + 1) + (xcd - r) * q)   \
                 + (orig >> 3);                                              \
  const int b   = wgid / (GX * GY);                                          \
  const int rem = wgid - b * (GX * GY);                                      \
  const int tyb = rem / GX;                                                  \
  const int txb = rem - tyb * GX;                                            \
  const int X0 = txb * TSX;                                                  \
  const int Y0 = tyb * TSY;                                                  \
  const int t   = threadIdx.x;                                               \
  const int x   = X0 + ((t & 15) << 2);                                      \
  const int y   = Y0 + (t >> 4);                                             \
  const int pix = y * Wd + x;

// Weights + clamped LDS addrs + fallback mask + packed corner coords.
#define PRECOMPUTE_WEIGHTS()                                                 \
  float4 fxv = *reinterpret_cast<const float4*>(fl + pix);                   \
  float4 fyv = *reinterpret_cast<const float4*>(fl + HW + pix);              \
  float w00[4], w10[4], w01[4], w11[4];                                      \
  int lA[4]; uint32_t pxy[4]; int fbm = 0;                                   \
  _Pragma("unroll")                                                          \
  for (int j = 0; j < 4; ++j) {                                              \
    float fx = (j==0)?fxv.x:(j==1)?fxv.y:(j==2)?fxv.z:fxv.w;                 \
    float fy = (j==0)?fyv.x:(j==1)?fyv.y:(j==2)?fyv.z:fyv.w;                 \
    float gx = (float)(x + j) + fx;                                          \
    float gy = (float)y + fy;                                                \
    float x0f = floorf(gx), y0f = floorf(gy);                                \
    float wx = gx - x0f, wy = gy - y0f;                                      \
    bool vx0 = (x0f >= 0.f) && (x0f <= (float)(Wd - 1));                     \
    bool vx1 = (x0f + 1.f >= 0.f) && (x0f + 1.f <= (float)(Wd - 1));         \
    bool vy0 = (y0f >= 0.f) && (y0f <= (float)(Hd - 1));                     \
    bool vy1 = (y0f + 1.f >= 0.f) && (y0f + 1.f <= (float)(Hd - 1));         \
    w00[j] = (1.f-wx)*(1.f-wy) * ((vx0 && vy0) ? 1.f : 0.f);                 \
    w10[j] = wx*(1.f-wy)       * ((vx1 && vy0) ? 1.f : 0.f);                 \
    w01[j] = (1.f-wx)*wy       * ((vx0 && vy1) ? 1.f : 0.f);                 \
    w11[j] = wx*wy             * ((vx1 && vy1) ? 1.f : 0.f);                 \
    int ix0 = (int)x0f;                                                      \
    int iy0 = (int)y0f;                                                      \
    int lx = ix0 - (X0 - HALO);                                              \
    int ly = iy0 - (Y0 - HALO);                                              \
    bool ft = (lx >= 0) & (lx <= TWX - 2) & (ly >= 0) & (ly <= TWY - 2);     \
    if (!ft) fbm |= (1 << j);                                                \
    int lxc = min(max(lx, 0), TWX - 2), lyc = min(max(ly, 0), TWY - 2);      \
    lA[j] = (lyc * TWX + lxc) * 4;                                           \
    uint32_t px_ = (uint32_t)min(max(ix0 + 128, 0), 65535);                  \
    uint32_t py_ = (uint32_t)min(max(iy0 + 128, 0), 65535);                  \
    pxy[j] = px_ | (py_ << 16);                                              \
  }

#define PRECOMPUTE_GOFF()                                                    \
  const int lane = t & 63;                                                   \
  const int wv   = t >> 6;                                                   \
  const int nck  = (wv < 4) ? 3 : 2;                                         \
  int goff[3];                                                               \
  _Pragma("unroll")                                                          \
  for (int k = 0; k < 3; ++k) {                                              \
    int ck = wv + 8 * k;                                                     \
    if (ck < NCHUNK) {                                                       \
      int foff = ck * 256 + lane * 4;                                        \
      int ly = foff / TWX;                                                   \
      int lx = foff - ly * TWX;                                              \
      int gxc = min(max(X0 - HALO + lx, 0), Wd - 4);                         \
      int gyc = min(max(Y0 - HALO + ly, 0), Hd - 1);                         \
      goff[k] = gyc * Wd + gxc;                                              \
    }                                                                        \
  }

// =============== pipelined fp32-source kernel (stage A + fallback) =========
// Quad-buffered GLL staging, counted vmcnt + raw s_barrier (T3/T4).
// Per-wave vmem queue/phase: nck fills + 1 store -> steady wait N = 2*nck+3.
#define WAITV(n3, n2)                                                        \
  if (wv < 4) { asm volatile("s_waitcnt vmcnt(" #n3 ")" ::: "memory"); }     \
  else        { asm volatile("s_waitcnt vmcnt(" #n2 ")" ::: "memory"); }

#define PHASE(c, n3, n2)                                                     \
  WAITV(n3, n2);                                                             \
  __builtin_amdgcn_s_barrier();                                              \
  __builtin_amdgcn_sched_barrier(0);                                         \
  if ((c) + 3 < Cd) fillq(((c) + 3) & 3, (c) + 3);                           \
  comp(c);

__global__ __launch_bounds__(512, 4) void warp_pipe(
    Job j0, Job j1, Job j2, Job j3, Job j4)
{
  __shared__ float tile[4 * TILE_F];   // 80 KB -> 2 blocks/CU

  const int jb = blockIdx.y;
  Job J = j0;
  if      (jb == 1) J = j1;
  else if (jb == 2) J = j2;
  else if (jb == 3) J = j3;
  else if (jb == 4) J = j4;

  DECODE_TILE();

  const float* sF32 = (const float*)J.s + (long)b * J.ss;
  float*       dF32 = (float*)J.d + (long)b * J.ds;
  uint16_t*    dB16 = (uint16_t*)J.d + (long)b * J.ds;
  const bool dBF = J.dBF != 0;

  if (J.fl == nullptr) {   // plain fp32 copy job (frame 0); no barriers
#pragma unroll
    for (int c = 0; c < Cd; ++c)
      *reinterpret_cast<float4*>(dF32 + (long)c * HW + pix)
          = *reinterpret_cast<const float4*>(sF32 + (long)c * HW + pix);
    return;
  }

  const float* fl = J.fl + (long)b * FLOW_BSTRIDE;
  PRECOMPUTE_WEIGHTS();
  PRECOMPUTE_GOFF();

  auto fillq = [&](int buf, int c) {
    const float* sC = sF32 + (long)c * HW;
    float* base = &tile[buf * TILE_F];
#pragma unroll
    for (int k = 0; k < 3; ++k) {
      if (k < nck) {
        __builtin_amdgcn_global_load_lds(
            (__attribute__((address_space(1))) void*)(void*)(sC + goff[k]),
            (__attribute__((address_space(3))) void*)&base[(wv + 8 * k) * 256],
            16, 0, 0);
      }
    }
  };

  auto comp = [&](int c) {
    const float* tb = &tile[(c & 3) * TILE_F];
    float ov[4];
#pragma unroll
    for (int j = 0; j < 4; ++j) {
      F2 r0 = *(const F2*)((const char*)tb + lA[j]);
      F2 r1 = *(const F2*)((const char*)tb + lA[j] + TWX * 4);
      ov[j] = (w00[j] * r0.x + w10[j] * r0.y) + (w01[j] * r1.x + w11[j] * r1.y);
    }
    if (dBF) {
      uint p0 = f2bf_bits(ov[0]) | (f2bf_bits(ov[1]) << 16);
      uint p1 = f2bf_bits(ov[2]) | (f2bf_bits(ov[3]) << 16);
      *reinterpret_cast<uint2*>(dB16 + (long)c * HW + pix) = make_uint2(p0, p1);
    } else {
      *reinterpret_cast<float4*>(dF32 + (long)c * HW + pix)
          = make_float4(ov[0], ov[1], ov[2], ov[3]);
    }
  };

  // Prologue: 3 phases in flight before first consume.
  fillq(0, 0); fillq(1, 1); fillq(2, 2);

  PHASE(0, 6, 4)  PHASE(1, 7, 5)  PHASE(2, 8, 6)
  PHASE(3, 9, 7)  PHASE(4, 9, 7)  PHASE(5, 9, 7)
  PHASE(6, 9, 7)  PHASE(7, 9, 7)  PHASE(8, 9, 7)
  PHASE(9, 9, 7)  PHASE(10, 9, 7) PHASE(11, 9, 7)
  PHASE(12, 9, 7) PHASE(13, 9, 7)
  PHASE(14, 6, 5) PHASE(15, 3, 3)

  // Epilogue: exact global re-gather for out-of-tile pixels (rare), after a
  // full drain so the scalar store wins over the phase store.
  if (fbm) {
    asm volatile("s_waitcnt vmcnt(0)" ::: "memory");
    for (int c = 0; c < Cd; ++c) {
      const float* sC = sF32 + (long)c * HW;
#pragma unroll
      for (int j = 0; j < 4; ++j) {
        if (fbm & (1 << j)) {
          uint32_t p = pxy[j];
          int ix0 = (int)(p & 0xffffu) - 128;
          int iy0 = (int)(p >> 16) - 128;
          int xc0 = min(max(ix0, 0), Wd - 1), xc1 = min(max(ix0 + 1, 0), Wd - 1);
          int yc0 = min(max(iy0, 0), Hd - 1), yc1 = min(max(iy0 + 1, 0), Hd - 1);
          float v = w00[j] * sC[yc0 * Wd + xc0] + w10[j] * sC[yc0 * Wd + xc1]
                  + w01[j] * sC[yc1 * Wd + xc0] + w11[j] * sC[yc1 * Wd + xc1];
          if (dBF) dB16[(long)c * HW + pix + j] = (uint16_t)f2bf_bits(v);
          else     dF32[(long)c * HW + pix + j] = v;
        }
      }
    }
  }
}

// =============== bf16-source kernel (stages B/C/D) — round-8 proven ========
__global__ __launch_bounds__(512) void warp_bf16(
    Job j0, Job j1, Job j2, Job j3, Job j4)
{
  __shared__ float tile[2][TILE_F];   // 40 KB

  const int jb = blockIdx.y;
  Job J = j0;
  if      (jb == 1) J = j1;
  else if (jb == 2) J = j2;
  else if (jb == 3) J = j3;
  else if (jb == 4) J = j4;

  DECODE_TILE();

  const uint16_t* sB16 = (const uint16_t*)J.s + (long)b * J.ss;
  float*          dF32 = (float*)J.d + (long)b * J.ds;
  uint16_t*       dB16 = (uint16_t*)J.d + (long)b * J.ds;
  const bool dBF = J.dBF != 0;

  const float* fl = J.fl + (long)b * FLOW_BSTRIDE;
  PRECOMPUTE_WEIGHTS();
  PRECOMPUTE_GOFF();

  // bf16 fill: reg-staged (load early / cvt+ds_write late).
  uint2 ld[3];
  auto loadB = [&](int c) {
    const uint* gp = (const uint*)(sB16 + (long)c * HW);
#pragma unroll
    for (int k = 0; k < 3; ++k)
      if (k < nck) ld[k] = *(const uint2*)(gp + (goff[k] >> 1));
  };
  auto writeB = [&](int nb) {
#pragma unroll
    for (int k = 0; k < 3; ++k) {
      if (k < nck) {
        float4 f;
        f.x = __uint_as_float(ld[k].x << 16);
        f.y = __uint_as_float(ld[k].x & 0xFFFF0000u);
        f.z = __uint_as_float(ld[k].y << 16);
        f.w = __uint_as_float(ld[k].y & 0xFFFF0000u);
        *reinterpret_cast<float4*>(&tile[nb][(wv + 8 * k) * 256 + lane * 4]) = f;
      }
    }
  };

  loadB(0); writeB(0);

#pragma unroll
  for (int c = 0; c < Cd; ++c) {
    __syncthreads();
    const bool pre = (c + 1 < Cd);
    if (pre) loadB(c + 1);

    const float* tb = tile[c & 1];
    float ov[4];
#pragma unroll
    for (int j = 0; j < 4; ++j) {
      float v;
      if (!(fbm & (1 << j))) {
        F2 r0 = *(const F2*)((const char*)tb + lA[j]);
        F2 r1 = *(const F2*)((const char*)tb + lA[j] + TWX * 4);
        v = (w00[j] * r0.x + w10[j] * r0.y) + (w01[j] * r1.x + w11[j] * r1.y);
      } else {
        uint32_t p = pxy[j];
        int ix0 = (int)(p & 0xffffu) - 128;
        int iy0 = (int)(p >> 16) - 128;
        int xc0 = min(max(ix0, 0), Wd - 1), xc1 = min(max(ix0 + 1, 0), Wd - 1);
        int yc0 = min(max(iy0, 0), Hd - 1), yc1 = min(max(iy0 + 1, 0), Hd - 1);
        const uint16_t* su = sB16 + (long)c * HW;
        float v00 = __uint_as_float((uint)su[yc0 * Wd + xc0] << 16);
        float v10 = __uint_as_float((uint)su[yc0 * Wd + xc1] << 16);
        float v01 = __uint_as_float((uint)su[yc1 * Wd + xc0] << 16);
        float v11 = __uint_as_float((uint)su[yc1 * Wd + xc1] << 16);
        v = w00[j] * v00 + w10[j] * v10 + w01[j] * v01 + w11[j] * v11;
      }
      ov[j] = v;
    }
    if (dBF) {
      uint p0 = f2bf_bits(ov[0]) | (f2bf_bits(ov[1]) << 16);
      uint p1 = f2bf_bits(ov[2]) | (f2bf_bits(ov[3]) << 16);
      *reinterpret_cast<uint2*>(dB16 + (long)c * HW + pix) = make_uint2(p0, p1);
    } else {
      *reinterpret_cast<float4*>(dF32 + (long)c * HW + pix)
          = make_float4(ov[0], ov[1], ov[2], ov[3]);
    }
    if (pre) writeB((c + 1) & 1);
  }
}

extern "C" void kernel_launch(void* const* d_in, const int* in_sizes, int n_in,
                              void* d_out, int out_size, void* d_ws, size_t ws_size,
                              hipStream_t stream) {
  const float* feat = (const float*)d_in[0];
  const float* mv   = (const float*)d_in[1];
  float*       out  = (float*)d_out;

  dim3 block(512, 1, 1);
  const long FB = FRAME_BSTRIDE;
  auto mkjob = [](const void* s, long ss, void* d, long ds, const float* fl,
                  int sBF, int dBF) {
    Job j; j.s = s; j.ss = ss; j.d = d; j.ds = ds; j.fl = fl;
    j.sBF = sBF; j.dBF = dBF; return j;
  };
  Job Z = mkjob(nullptr, 0, nullptr, 0, nullptr, 0, 0);
  const float* flj[4] = { mv + 0L * 2 * HW, mv + 1L * 2 * HW,
                          mv + 2L * 2 * HW, mv + 3L * 2 * HW };

  auto launchP = [&](int nj, Job a, Job b, Job c, Job d, Job e) {
    warp_pipe<<<dim3(NWG, nj, 1), block, 0, stream>>>(a, b, c, d, e);
  };
  auto launchB = [&](int nj, Job a, Job b, Job c) {
    warp_bf16<<<dim3(NWG, nj, 1), block, 0, stream>>>(a, b, c, Z, Z);
  };

  const size_t need = (size_t)(4 * CHW) * Bd * sizeof(uint16_t);  // 134 MB

  if (ws_size >= need) {
    uint16_t* W  = (uint16_t*)d_ws;
    const long WB = 4 * CHW;               // ws batch stride (bf16 elems)
    uint16_t* wa = W + 0 * CHW;
    uint16_t* wb = W + 1 * CHW;
    uint16_t* wd = W + 2 * CHW;
    uint16_t* wc = W + 3 * CHW;
    uint16_t* we = (uint16_t*)(out + 4 * CHW);   // out4 slot as bf16 scratch
    const long EB = 2 * FB;                // out batch stride in bf16 elems

    // A (pipelined): f1 final; f2->a, f3->b, f4->d (bf16); frame-0 copy.
    launchP(5,
      mkjob(feat + 1 * CHW, FB, out + 1 * CHW, FB, flj[0], 0, 0),
      mkjob(feat + 2 * CHW, FB, wa, WB, flj[1], 0, 1),
      mkjob(feat + 3 * CHW, FB, wb, WB, flj[2], 0, 1),
      mkjob(feat + 4 * CHW, FB, wd, WB, flj[3], 0, 1),
      mkjob(feat, FB, out, FB, nullptr, 0, 0));
    // B: a->out2 final; b->c (bf16); d->e (bf16, in out4 slot).
    launchB(3,
      mkjob(wa, WB, out + 2 * CHW, FB, flj[0], 1, 0),
      mkjob(wb, WB, wc, WB, flj[1], 1, 1),
      mkjob(wd, WB, we, EB, flj[2], 1, 1));
    // C: c->out3 final; e->f (bf16, reuse slot a).
    launchB(2,
      mkjob(wc, WB, out + 3 * CHW, FB, flj[0], 1, 0),
      mkjob(we, EB, wa, WB, flj[1], 1, 1), Z);
    // D: f->out4 final (overwrites e, dead).
    launchB(1, mkjob(wa, WB, out + 4 * CHW, FB, flj[0], 1, 0), Z, Z);
  } else {
    // Fallback: all-fp32 via the pipelined kernel, out0 slot as scratch.
    float* S = out;
    auto w1 = [&](const float* s, float* d, int j) {
      launchP(1, mkjob(s, FB, d, FB, flj[j], 0, 0), Z, Z, Z, Z);
    };
    w1(feat + 1 * CHW, out + 1 * CHW, 0);
    w1(feat + 2 * CHW, S, 1);
    w1(S, out + 2 * CHW, 0);
    w1(feat + 3 * CHW, out + 3 * CHW, 2);
    w1(out + 3 * CHW, S, 1);
    w1(S, out + 3 * CHW, 0);
    w1(feat + 4 * CHW, S, 3);
    w1(S, out + 4 * CHW, 2);
    w1(out + 4 * CHW, S, 1);
    w1(S, out + 4 * CHW, 0);
    launchP(1, mkjob(feat, FB, out, FB, nullptr, 0, 0), Z, Z, Z, Z);
  }
}